// Round 4
// baseline (834.465 us; speedup 1.0000x reference)
//
#include <hip/hip_runtime.h>
#include <cstdint>

typedef __attribute__((ext_vector_type(8))) short bf16x8;
typedef __attribute__((ext_vector_type(4))) float f32x4;
typedef unsigned short u16;
typedef unsigned int u32;

constexpr int D   = 2048;
constexpr int H   = 16;
constexpr int HD  = 128;
constexpr int BATCH = 4;
constexpr int S   = 2048;
constexpr int ROWS = BATCH * S;   // 8192
constexpr int N3D = 3 * D;        // 6144
constexpr int QKW = 2 * D;        // 4096: width of Q|K buffer

__device__ __forceinline__ u16 f2bf(float f) {
    union { float f; u32 u; } v; v.f = f;
    u32 r = v.u + 0x7FFFu + ((v.u >> 16) & 1u);
    return (u16)(r >> 16);
}

__device__ __forceinline__ void gld_lds16(const u16* g, u16* l) {
    __builtin_amdgcn_global_load_lds(
        (const __attribute__((address_space(1))) void*)g,
        (__attribute__((address_space(3))) void*)l, 16, 0, 0);
}

// ---------------------------------------------------------------- LayerNorm
__global__ __launch_bounds__(256) void ln_bf16_kernel(
    const float* __restrict__ x, const float* __restrict__ gamma,
    const float* __restrict__ beta, u16* __restrict__ out)
{
    const int row = blockIdx.x;
    const int t = threadIdx.x;
    const float* xr = x + (size_t)row * D;
    float4 a = ((const float4*)xr)[2*t];
    float4 b = ((const float4*)xr)[2*t+1];
    float s  = a.x+a.y+a.z+a.w + b.x+b.y+b.z+b.w;
    float ss = a.x*a.x+a.y*a.y+a.z*a.z+a.w*a.w + b.x*b.x+b.y*b.y+b.z*b.z+b.w*b.w;
    #pragma unroll
    for (int off = 32; off > 0; off >>= 1) {
        s  += __shfl_down(s, off);
        ss += __shfl_down(ss, off);
    }
    __shared__ float red[8];
    const int wave = t >> 6, lane = t & 63;
    if (lane == 0) { red[wave] = s; red[4+wave] = ss; }
    __syncthreads();
    const float mu   = (red[0]+red[1]+red[2]+red[3]) * (1.0f/D);
    const float var  = (red[4]+red[5]+red[6]+red[7]) * (1.0f/D) - mu*mu;
    const float rstd = rsqrtf(var + 1e-5f);
    float4 g0  = ((const float4*)gamma)[2*t];
    float4 g1  = ((const float4*)gamma)[2*t+1];
    float4 be0 = ((const float4*)beta)[2*t];
    float4 be1 = ((const float4*)beta)[2*t+1];
    union { uint4 v; u16 e[8]; } o;
    o.e[0] = f2bf((a.x-mu)*rstd*g0.x + be0.x);
    o.e[1] = f2bf((a.y-mu)*rstd*g0.y + be0.y);
    o.e[2] = f2bf((a.z-mu)*rstd*g0.z + be0.z);
    o.e[3] = f2bf((a.w-mu)*rstd*g0.w + be0.w);
    o.e[4] = f2bf((b.x-mu)*rstd*g1.x + be1.x);
    o.e[5] = f2bf((b.y-mu)*rstd*g1.y + be1.y);
    o.e[6] = f2bf((b.z-mu)*rstd*g1.z + be1.z);
    o.e[7] = f2bf((b.w-mu)*rstd*g1.w + be1.w);
    ((uint4*)(out + (size_t)row*D))[t] = o.v;
}

// ------------------------------------------- transpose + fp32->bf16 weights
__global__ __launch_bounds__(256) void transpose_bf16_kernel(
    const float* __restrict__ in, u16* __restrict__ out, int K, int N)
{
    __shared__ u16 tile[64][65];
    const int tn0 = blockIdx.x * 64;
    const int tk0 = blockIdx.y * 64;
    const int t = threadIdx.x;
    const int tx = t & 63;
    const int ty = t >> 6;
    #pragma unroll
    for (int i = 0; i < 16; i++) {
        int k = ty + i*4;
        tile[k][tx] = f2bf(in[(size_t)(tk0+k)*N + tn0 + tx]);
    }
    __syncthreads();
    #pragma unroll
    for (int i = 0; i < 16; i++) {
        int n = ty + i*4;
        out[(size_t)(tn0+n)*K + tk0 + tx] = tile[tx][n];
    }
}

// ---------------------------------------------------------------- GEMM 256²
// 256x256 tile, BK=32 sub-tiles in a 4-slot LDS ring (16 KB/slot/operand).
// 8 waves (2M x 4N), per-wave output 128x64.
// Single barrier per K-step: [vmcnt(8) wait][s_barrier][STAGE kt+3]
// [ds_read + 2x16 MFMA][lgkmcnt(0)].  Never vmcnt(0) in the loop (T4).
// XOR bank swizzle (measured-zero conflicts, r3):
//   LDS[row][blk] = global[row][blk ^ ((row>>1)&3)]
// staged via swizzled GLOBAL source, read back rblk = (lq ^ ((lr>>1)&3))*8.
// T1: XCD-chunked 1-D grid swizzle — each XCD owns a contiguous band of 4
// m-blocks (A working set 4 MB = its L2) so A-panel re-reads become L2 hits.
constexpr int BM = 256, BN = 256, BK = 32;

template<int MODE>
__global__ __launch_bounds__(512, 2) void gemm256_kernel(
    const u16* __restrict__ A, const u16* __restrict__ Bt,
    const float* __restrict__ bias, void* __restrict__ Cout,
    u16* __restrict__ vtb, int M, int N, int K)
{
    __shared__ u16 sA[4 * 8192];   // 4 slots x [256][32] bf16 = 64 KB
    __shared__ u16 sB[4 * 8192];   // 64 KB

    const int t = threadIdx.x;
    const int wave = t >> 6, lane = t & 63;
    const int lr = lane & 15, lq = lane >> 4;
    const int wm = wave >> 2, wn = wave & 3;          // 2 x 4 wave grid

    // XCD-chunked swizzle (nwg % 8 == 0 for both GEMMs -> bijective)
    const int flat = blockIdx.x;
    const int chunk = gridDim.x >> 3;
    const int wgid = (flat & 7) * chunk + (flat >> 3);
    const int nbx = N / BN;
    const int mb = wgid / nbx, nb = wgid % nbx;
    const int m0 = mb * BM, n0 = nb * BN;

    // staging: granule g (16 B) -> LDS elems [g*8, g*8+8) (linear dest),
    // global source row g>>2, col-block (g&3) ^ ((g>>3)&3)  (XOR swizzle).
    const int g0 = t, g1 = t + 512;
    const int cs0 = ((g0 & 3) ^ ((g0 >> 3) & 3)) * 8;
    const int cs1 = ((g1 & 3) ^ ((g1 >> 3) & 3)) * 8;
    const u16* gA0 = A  + (size_t)(m0 + (g0 >> 2)) * K + cs0;
    const u16* gA1 = A  + (size_t)(m0 + (g1 >> 2)) * K + cs1;
    const u16* gB0 = Bt + (size_t)(n0 + (g0 >> 2)) * K + cs0;
    const u16* gB1 = Bt + (size_t)(n0 + (g1 >> 2)) * K + cs1;

    f32x4 acc[8][4];
    #pragma unroll
    for (int i = 0; i < 8; i++)
        #pragma unroll
        for (int j = 0; j < 4; j++)
            acc[i][j] = (f32x4)(0.0f);

    const int NT = K / BK;   // 64

    auto STAGE = [&](int slot, int kt) {
        u16* a = sA + slot * 8192 + wave * 512;
        u16* b = sB + slot * 8192 + wave * 512;
        const int ko = kt * BK;
        gld_lds16(gA0 + ko, a);
        gld_lds16(gA1 + ko, a + 4096);
        gld_lds16(gB0 + ko, b);
        gld_lds16(gB1 + ko, b + 4096);
    };

    // prologue: fill slots 0,1,2 (12 loads in flight)
    STAGE(0, 0); STAGE(1, 1); STAGE(2, 2);

    // fragment read: swizzled block for global block lq of row ..+lr
    const int rblk = (lq ^ ((lr >> 1) & 3)) * 8;

    for (int kt = 0; kt < NT; ++kt) {
        // drain own tile-kt loads (8 newer stay in flight), publish via BAR.
        asm volatile("s_waitcnt vmcnt(8)" ::: "memory");
        __builtin_amdgcn_s_barrier();
        __builtin_amdgcn_sched_barrier(0);
        // prefetch tile kt+3 into slot (kt+3)&3 == (kt-1)&3, whose readers
        // all finished (lgkmcnt(0) below) before arriving at this barrier.
        const int tp = (kt + 3 < NT) ? (kt + 3) : (NT - 1);
        STAGE((kt + 3) & 3, tp);

        const u16* tAp = sA + (kt & 3) * 8192 + (wm * 128) * BK + rblk;
        const u16* tBp = sB + (kt & 3) * 8192 + (wn * 64)  * BK + rblk;

        bf16x8 bfr[4], af[4];
        #pragma unroll
        for (int nt = 0; nt < 4; nt++)
            bfr[nt] = *(const bf16x8*)(tBp + (nt * 16 + lr) * BK);
        #pragma unroll
        for (int mt = 0; mt < 4; mt++)
            af[mt] = *(const bf16x8*)(tAp + (mt * 16 + lr) * BK);
        __builtin_amdgcn_s_setprio(1);
        #pragma unroll
        for (int mt = 0; mt < 4; mt++)
            #pragma unroll
            for (int nt = 0; nt < 4; nt++)
                acc[mt][nt] = __builtin_amdgcn_mfma_f32_16x16x32_bf16(
                    af[mt], bfr[nt], acc[mt][nt], 0, 0, 0);
        __builtin_amdgcn_s_setprio(0);
        #pragma unroll
        for (int mt = 0; mt < 4; mt++)
            af[mt] = *(const bf16x8*)(tAp + (64 + mt * 16 + lr) * BK);
        __builtin_amdgcn_s_setprio(1);
        #pragma unroll
        for (int mt = 0; mt < 4; mt++)
            #pragma unroll
            for (int nt = 0; nt < 4; nt++)
                acc[4 + mt][nt] = __builtin_amdgcn_mfma_f32_16x16x32_bf16(
                    af[mt], bfr[nt], acc[4 + mt][nt], 0, 0, 0);
        __builtin_amdgcn_s_setprio(0);
        // all of this iteration's LDS reads must be complete (not just
        // issued) before any wave can pass the next barrier and overwrite.
        asm volatile("s_waitcnt lgkmcnt(0)" ::: "memory");
        __builtin_amdgcn_sched_barrier(0);
    }

    #pragma unroll
    for (int i = 0; i < 8; i++) {
        const int row0 = m0 + wm * 128 + (i >> 2) * 64 + (i & 3) * 16 + lq * 4;
        #pragma unroll
        for (int nt = 0; nt < 4; nt++) {
            const int col = n0 + wn * 64 + nt * 16 + lr;
            const float bv = bias[col];
            float v[4];
            #pragma unroll
            for (int r = 0; r < 4; r++) v[r] = acc[i][nt][r] + bv;
            if (MODE == 0) {
                #pragma unroll
                for (int r = 0; r < 4; r++)
                    ((float*)Cout)[(size_t)(row0 + r) * N + col] = v[r];
            } else {
                if (n0 < QKW) {
                    #pragma unroll
                    for (int r = 0; r < 4; r++)
                        ((u16*)Cout)[(size_t)(row0 + r) * QKW + col] = f2bf(v[r]);
                } else {
                    const int vcol = col - QKW;          // 0..2047
                    const int b = row0 >> 11, s0 = row0 & 2047;
                    ushort4 pk;
                    pk.x = f2bf(v[0]); pk.y = f2bf(v[1]);
                    pk.z = f2bf(v[2]); pk.w = f2bf(v[3]);
                    *(ushort4*)(vtb + ((size_t)(b*H + (vcol >> 7)) * HD
                                       + (vcol & 127)) * S + s0) = pk;
                }
            }
        }
    }
}

// ---------------------------------------------------------- flash attention
// T14 async-STAGE: K/V tile kt+1 global loads issued right after the
// publish barrier of kt; the whole QK^T/softmax/PV of kt hides the latency
// (the ds_write at the next loop top forces the vmcnt wait). T5 setprio
// around both MFMA clusters.
constexpr int TQ = 64, TK = 64;
constexpr int KPAD = 136;
constexpr int VPAD = 72;
constexpr int PPAD = 72;

__global__ __launch_bounds__(256) void attn_kernel(
    const u16* __restrict__ qkb, const u16* __restrict__ vtb,
    u16* __restrict__ ctx)
{
    __shared__ u16 sK[TK * KPAD];
    __shared__ u16 sVT[HD * VPAD];
    __shared__ u16 sP[4 * 16 * PPAD];

    const int flat = blockIdx.x;
    const int qt = 31 - (flat >> 6);
    const int bh = flat & 63;
    const int b  = bh >> 4, h = bh & 15;
    const int q0 = qt * TQ;
    const int t = threadIdx.x;
    const int wave = t >> 6, lane = t & 63;
    const int lr = lane & 15, lq = lane >> 4;

    const u16* baseQK = qkb + (size_t)b * S * QKW + h * HD;
    const u16* baseVT = vtb + (size_t)bh * HD * S;

    const int qrow = q0 + wave * 16 + lr;
    bf16x8 qf[4];
    #pragma unroll
    for (int kc = 0; kc < 4; kc++)
        qf[kc] = *(const bf16x8*)(baseQK + (size_t)qrow * QKW + kc*32 + lq*8);

    float m_r[4], l_r[4];
    f32x4 o[8];
    #pragma unroll
    for (int r = 0; r < 4; r++) { m_r[r] = -1e30f; l_r[r] = 0.0f; }
    #pragma unroll
    for (int j = 0; j < 8; j++) o[j] = (f32x4)(0.0f);

    const float scale = 0.08838834764831845f; // 1/sqrt(128)
    const int nkt = qt + 1;

    // staging registers (T14): this thread's 4 K-granules + 4 V-granules
    const int kr_row = t >> 4, kr_col = (t & 15) * 8;   // K: +64 rows per i
    const int vr_row = t >> 3, vr_col = (t & 7) * 8;    // V: +32 rows per i
    uint4 kreg[4], vreg[4];
    auto LOADKV = [&](int kt) {
        #pragma unroll
        for (int i = 0; i < 4; i++)
            kreg[i] = *(const uint4*)(baseQK + D
                + (size_t)(kt*TK + ((kr_row + i*16) & 63)) * QKW
                + kr_col + ((kr_row + i*16) >> 6) * 0);
        #pragma unroll
        for (int i = 0; i < 4; i++)
            vreg[i] = *(const uint4*)(baseVT
                + (size_t)(vr_row + i*32) * S + kt*TK + vr_col);
    };
    // K rows: i covers rows {t>>4 + i*16}; 256 threads*4 = 1024 granules
    // = 64 rows x 16 col-blocks  ✓ (row = (t + i*256)>>4 = kr_row + i*16)
    LOADKV(0);

    for (int kt = 0; kt < nkt; kt++) {
        __syncthreads();   // prev iteration's LDS readers done
        #pragma unroll
        for (int i = 0; i < 4; i++)
            *(uint4*)(sK + (kr_row + i*16) * KPAD + kr_col) = kreg[i];
        #pragma unroll
        for (int i = 0; i < 4; i++)
            *(uint4*)(sVT + (vr_row + i*32) * VPAD + vr_col) = vreg[i];
        __syncthreads();   // published
        if (kt + 1 < nkt) LOADKV(kt + 1);   // hides under compute below

        f32x4 sc[4];
        #pragma unroll
        for (int nt = 0; nt < 4; nt++) sc[nt] = (f32x4)(0.0f);
        __builtin_amdgcn_s_setprio(1);
        #pragma unroll
        for (int nt = 0; nt < 4; nt++)
            #pragma unroll
            for (int kc = 0; kc < 4; kc++) {
                bf16x8 kf = *(const bf16x8*)(sK + (nt*16 + lr) * KPAD + kc*32 + lq*8);
                sc[nt] = __builtin_amdgcn_mfma_f32_16x16x32_bf16(qf[kc], kf, sc[nt], 0, 0, 0);
            }
        __builtin_amdgcn_s_setprio(0);

        const bool diag = (kt == qt);
        float rowmax[4] = {-1e30f, -1e30f, -1e30f, -1e30f};
        const int qgb = q0 + wave*16 + lq*4;
        #pragma unroll
        for (int nt = 0; nt < 4; nt++)
            #pragma unroll
            for (int r = 0; r < 4; r++) {
                float sv = sc[nt][r] * scale;
                if (diag) {
                    const int kg = kt*TK + nt*16 + lr;
                    if (kg > qgb + r) sv = -1e30f;
                }
                sc[nt][r] = sv;
                rowmax[r] = fmaxf(rowmax[r], sv);
            }
        #pragma unroll
        for (int mask = 1; mask < 16; mask <<= 1)
            #pragma unroll
            for (int r = 0; r < 4; r++)
                rowmax[r] = fmaxf(rowmax[r], __shfl_xor(rowmax[r], mask));

        float alpha[4];
        #pragma unroll
        for (int r = 0; r < 4; r++) {
            float nm = fmaxf(m_r[r], rowmax[r]);
            alpha[r] = __expf(m_r[r] - nm);
            m_r[r] = nm;
        }

        u16* pw = sP + wave * 16 * PPAD;
        #pragma unroll
        for (int nt = 0; nt < 4; nt++) {
            #pragma unroll
            for (int r = 0; r < 4; r++) {
                float p = __expf(sc[nt][r] - m_r[r]);
                sc[nt][r] = p;
                pw[(lq*4 + r) * PPAD + nt*16 + lr] = f2bf(p);
            }
        }
        #pragma unroll
        for (int r = 0; r < 4; r++) {
            float psum = sc[0][r] + sc[1][r] + sc[2][r] + sc[3][r];
            l_r[r] = l_r[r] * alpha[r] + psum;
        }
        #pragma unroll
        for (int j = 0; j < 8; j++)
            #pragma unroll
            for (int r = 0; r < 4; r++)
                o[j][r] *= alpha[r];

        #pragma unroll
        for (int kc2 = 0; kc2 < 2; kc2++) {
            bf16x8 pa = *(const bf16x8*)(pw + lr * PPAD + kc2*32 + lq*8);
            __builtin_amdgcn_s_setprio(1);
            #pragma unroll
            for (int n2 = 0; n2 < 8; n2++) {
                bf16x8 vb = *(const bf16x8*)(sVT + (n2*16 + lr) * VPAD + kc2*32 + lq*8);
                o[n2] = __builtin_amdgcn_mfma_f32_16x16x32_bf16(pa, vb, o[n2], 0, 0, 0);
            }
            __builtin_amdgcn_s_setprio(0);
        }
    }

    #pragma unroll
    for (int mask = 1; mask < 16; mask <<= 1)
        #pragma unroll
        for (int r = 0; r < 4; r++)
            l_r[r] += __shfl_xor(l_r[r], mask);
    float inv_l[4];
    #pragma unroll
    for (int r = 0; r < 4; r++) inv_l[r] = 1.0f / l_r[r];
    #pragma unroll
    for (int n2 = 0; n2 < 8; n2++)
        #pragma unroll
        for (int r = 0; r < 4; r++) {
            const int qg = q0 + wave*16 + lq*4 + r;
            const float v = o[n2][r] * inv_l[r];
            ctx[(size_t)(b * S + qg) * D + h * HD + n2*16 + lr] = f2bf(v);
        }
}

// ---------------------------------------------------------------- launcher
extern "C" void kernel_launch(void* const* d_in, const int* in_sizes, int n_in,
                              void* d_out, int out_size, void* d_ws, size_t ws_size,
                              hipStream_t stream) {
    const float* hs    = (const float*)d_in[0];
    const float* gamma = (const float*)d_in[1];
    const float* beta  = (const float*)d_in[2];
    const float* Wqkv  = (const float*)d_in[3];
    const float* bqkv  = (const float*)d_in[4];
    const float* Wproj = (const float*)d_in[5];
    const float* bproj = (const float*)d_in[6];

    char* ws = (char*)d_ws;
    size_t off = 0;
    u16* xb   = (u16*)(ws + off); off += (size_t)ROWS * D * 2;    // 32 MiB
    u16* wtq  = (u16*)(ws + off); off += (size_t)N3D * D * 2;     // 24 MiB
    u16* wtp  = (u16*)(ws + off); off += (size_t)D * D * 2;       //  8 MiB
    u16* qkb  = (u16*)(ws + off); off += (size_t)ROWS * QKW * 2;  // 64 MiB
    u16* vtb  = (u16*)(ws + off); off += (size_t)ROWS * D * 2;    // 32 MiB
    u16* ctxb = (u16*)(ws + off);                                  // 32 MiB

    ln_bf16_kernel<<<ROWS, 256, 0, stream>>>(hs, gamma, beta, xb);
    transpose_bf16_kernel<<<dim3(N3D/64, D/64), 256, 0, stream>>>(Wqkv, wtq, D, N3D);
    transpose_bf16_kernel<<<dim3(D/64,   D/64), 256, 0, stream>>>(Wproj, wtp, D, D);
    gemm256_kernel<2><<<dim3((N3D/BN) * (ROWS/BM)), 512, 0, stream>>>(
        xb, wtq, bqkv, qkb, vtb, ROWS, N3D, D);
    attn_kernel<<<dim3((S/TQ) * BATCH * H), 256, 0, stream>>>(qkb, vtb, ctxb);
    gemm256_kernel<0><<<dim3((D/BN) * (ROWS/BM)), 512, 0, stream>>>(
        ctxb, wtp, bproj, (float*)d_out, nullptr, ROWS, D, D);
}

// Round 5
// 681.285 us; speedup vs baseline: 1.2248x; 1.2248x over previous
//
#include <hip/hip_runtime.h>
#include <cstdint>

typedef __attribute__((ext_vector_type(8))) short bf16x8;
typedef __attribute__((ext_vector_type(4))) float f32x4;
typedef unsigned short u16;
typedef unsigned int u32;

constexpr int D   = 2048;
constexpr int H   = 16;
constexpr int HD  = 128;
constexpr int BATCH = 4;
constexpr int S   = 2048;
constexpr int ROWS = BATCH * S;   // 8192
constexpr int N3D = 3 * D;        // 6144
constexpr int QKW = 2 * D;        // 4096: width of Q|K buffer

__device__ __forceinline__ u16 f2bf(float f) {
    union { float f; u32 u; } v; v.f = f;
    u32 r = v.u + 0x7FFFu + ((v.u >> 16) & 1u);
    return (u16)(r >> 16);
}

__device__ __forceinline__ void gld_lds16(const u16* g, u16* l) {
    __builtin_amdgcn_global_load_lds(
        (const __attribute__((address_space(1))) void*)g,
        (__attribute__((address_space(3))) void*)l, 16, 0, 0);
}

// ---------------------------------------------------------------- LayerNorm
__global__ __launch_bounds__(256) void ln_bf16_kernel(
    const float* __restrict__ x, const float* __restrict__ gamma,
    const float* __restrict__ beta, u16* __restrict__ out)
{
    const int row = blockIdx.x;
    const int t = threadIdx.x;
    const float* xr = x + (size_t)row * D;
    float4 a = ((const float4*)xr)[2*t];
    float4 b = ((const float4*)xr)[2*t+1];
    float s  = a.x+a.y+a.z+a.w + b.x+b.y+b.z+b.w;
    float ss = a.x*a.x+a.y*a.y+a.z*a.z+a.w*a.w + b.x*b.x+b.y*b.y+b.z*b.z+b.w*b.w;
    #pragma unroll
    for (int off = 32; off > 0; off >>= 1) {
        s  += __shfl_down(s, off);
        ss += __shfl_down(ss, off);
    }
    __shared__ float red[8];
    const int wave = t >> 6, lane = t & 63;
    if (lane == 0) { red[wave] = s; red[4+wave] = ss; }
    __syncthreads();
    const float mu   = (red[0]+red[1]+red[2]+red[3]) * (1.0f/D);
    const float var  = (red[4]+red[5]+red[6]+red[7]) * (1.0f/D) - mu*mu;
    const float rstd = rsqrtf(var + 1e-5f);
    float4 g0  = ((const float4*)gamma)[2*t];
    float4 g1  = ((const float4*)gamma)[2*t+1];
    float4 be0 = ((const float4*)beta)[2*t];
    float4 be1 = ((const float4*)beta)[2*t+1];
    union { uint4 v; u16 e[8]; } o;
    o.e[0] = f2bf((a.x-mu)*rstd*g0.x + be0.x);
    o.e[1] = f2bf((a.y-mu)*rstd*g0.y + be0.y);
    o.e[2] = f2bf((a.z-mu)*rstd*g0.z + be0.z);
    o.e[3] = f2bf((a.w-mu)*rstd*g0.w + be0.w);
    o.e[4] = f2bf((b.x-mu)*rstd*g1.x + be1.x);
    o.e[5] = f2bf((b.y-mu)*rstd*g1.y + be1.y);
    o.e[6] = f2bf((b.z-mu)*rstd*g1.z + be1.z);
    o.e[7] = f2bf((b.w-mu)*rstd*g1.w + be1.w);
    ((uint4*)(out + (size_t)row*D))[t] = o.v;
}

// ------------------------------------------- transpose + fp32->bf16 weights
__global__ __launch_bounds__(256) void transpose_bf16_kernel(
    const float* __restrict__ in, u16* __restrict__ out, int K, int N)
{
    __shared__ u16 tile[64][65];
    const int tn0 = blockIdx.x * 64;
    const int tk0 = blockIdx.y * 64;
    const int t = threadIdx.x;
    const int tx = t & 63;
    const int ty = t >> 6;
    #pragma unroll
    for (int i = 0; i < 16; i++) {
        int k = ty + i*4;
        tile[k][tx] = f2bf(in[(size_t)(tk0+k)*N + tn0 + tx]);
    }
    __syncthreads();
    #pragma unroll
    for (int i = 0; i < 16; i++) {
        int n = ty + i*4;
        out[(size_t)(tn0+n)*K + tk0 + tx] = tile[tx][n];
    }
}

// ---------------------------------------------------------------- GEMM 256²
// 256x256 tile, BK=32 sub-tiles in a 4-slot LDS ring (16 KB/slot/operand).
// 8 waves (2M x 4N), per-wave output 128x64.
// Single barrier per K-step: [vmcnt(8) wait][s_barrier][STAGE kt+3]
// [ds_read + 2x16 MFMA][lgkmcnt(0)].  Never vmcnt(0) in the loop (T4).
// XOR bank swizzle (measured-zero conflicts, r3):
//   LDS[row][blk] = global[row][blk ^ ((row>>1)&3)]
// staged via swizzled GLOBAL source, read back rblk = (lq ^ ((lr>>1)&3))*8.
// T1 (column-resident form): XCD x owns nbx/8 n-columns; its 32 CUs walk
// all 32 m-blocks of one column concurrently -> the 1 MB B-panel stays
// resident in x's L2 (re-hit 31x), only A streams from L3. flat%8 = XCD,
// flat>>3 = temporal rank within XCD (m157-verified dispatch mapping).
constexpr int BM = 256, BN = 256, BK = 32;

template<int MODE>
__global__ __launch_bounds__(512, 2) void gemm256_kernel(
    const u16* __restrict__ A, const u16* __restrict__ Bt,
    const float* __restrict__ bias, void* __restrict__ Cout,
    u16* __restrict__ vtb, int M, int N, int K)
{
    __shared__ u16 sA[4 * 8192];   // 4 slots x [256][32] bf16 = 64 KB
    __shared__ u16 sB[4 * 8192];   // 64 KB

    const int t = threadIdx.x;
    const int wave = t >> 6, lane = t & 63;
    const int lr = lane & 15, lq = lane >> 4;
    const int wm = wave >> 2, wn = wave & 3;          // 2 x 4 wave grid

    // XCD column-resident mapping (nbx % 8 == 0 for both GEMMs)
    const int flat = blockIdx.x;
    const int nbx = N / BN;            // 24 (QKV) or 8 (proj)
    const int nmb = M / BM;            // 32
    const int npx = nbx >> 3;          // n-columns per XCD
    const int xcd = flat & 7;
    const int local = flat >> 3;       // temporal order within this XCD
    const int nb = xcd * npx + local / nmb;
    const int mb = local % nmb;
    const int m0 = mb * BM, n0 = nb * BN;

    // staging: granule g (16 B) -> LDS elems [g*8, g*8+8) (linear dest),
    // global source row g>>2, col-block (g&3) ^ ((g>>3)&3)  (XOR swizzle).
    const int g0 = t, g1 = t + 512;
    const int cs0 = ((g0 & 3) ^ ((g0 >> 3) & 3)) * 8;
    const int cs1 = ((g1 & 3) ^ ((g1 >> 3) & 3)) * 8;
    const u16* gA0 = A  + (size_t)(m0 + (g0 >> 2)) * K + cs0;
    const u16* gA1 = A  + (size_t)(m0 + (g1 >> 2)) * K + cs1;
    const u16* gB0 = Bt + (size_t)(n0 + (g0 >> 2)) * K + cs0;
    const u16* gB1 = Bt + (size_t)(n0 + (g1 >> 2)) * K + cs1;

    f32x4 acc[8][4];
    #pragma unroll
    for (int i = 0; i < 8; i++)
        #pragma unroll
        for (int j = 0; j < 4; j++)
            acc[i][j] = (f32x4)(0.0f);

    const int NT = K / BK;   // 64

    auto STAGE = [&](int slot, int kt) {
        u16* a = sA + slot * 8192 + wave * 512;
        u16* b = sB + slot * 8192 + wave * 512;
        const int ko = kt * BK;
        gld_lds16(gA0 + ko, a);
        gld_lds16(gA1 + ko, a + 4096);
        gld_lds16(gB0 + ko, b);
        gld_lds16(gB1 + ko, b + 4096);
    };

    // prologue: fill slots 0,1,2 (12 loads in flight)
    STAGE(0, 0); STAGE(1, 1); STAGE(2, 2);

    // fragment read: swizzled block for global block lq of row ..+lr
    const int rblk = (lq ^ ((lr >> 1) & 3)) * 8;

    for (int kt = 0; kt < NT; ++kt) {
        // drain own tile-kt loads (8 newer stay in flight), publish via BAR.
        asm volatile("s_waitcnt vmcnt(8)" ::: "memory");
        __builtin_amdgcn_s_barrier();
        __builtin_amdgcn_sched_barrier(0);
        // prefetch tile kt+3 into slot (kt+3)&3 == (kt-1)&3, whose readers
        // all finished (lgkmcnt(0) below) before arriving at this barrier.
        const int tp = (kt + 3 < NT) ? (kt + 3) : (NT - 1);
        STAGE((kt + 3) & 3, tp);

        const u16* tAp = sA + (kt & 3) * 8192 + (wm * 128) * BK + rblk;
        const u16* tBp = sB + (kt & 3) * 8192 + (wn * 64)  * BK + rblk;

        bf16x8 bfr[4], af[4];
        #pragma unroll
        for (int nt = 0; nt < 4; nt++)
            bfr[nt] = *(const bf16x8*)(tBp + (nt * 16 + lr) * BK);
        #pragma unroll
        for (int mt = 0; mt < 4; mt++)
            af[mt] = *(const bf16x8*)(tAp + (mt * 16 + lr) * BK);
        __builtin_amdgcn_s_setprio(1);
        #pragma unroll
        for (int mt = 0; mt < 4; mt++)
            #pragma unroll
            for (int nt = 0; nt < 4; nt++)
                acc[mt][nt] = __builtin_amdgcn_mfma_f32_16x16x32_bf16(
                    af[mt], bfr[nt], acc[mt][nt], 0, 0, 0);
        __builtin_amdgcn_s_setprio(0);
        #pragma unroll
        for (int mt = 0; mt < 4; mt++)
            af[mt] = *(const bf16x8*)(tAp + (64 + mt * 16 + lr) * BK);
        __builtin_amdgcn_s_setprio(1);
        #pragma unroll
        for (int mt = 0; mt < 4; mt++)
            #pragma unroll
            for (int nt = 0; nt < 4; nt++)
                acc[4 + mt][nt] = __builtin_amdgcn_mfma_f32_16x16x32_bf16(
                    af[mt], bfr[nt], acc[4 + mt][nt], 0, 0, 0);
        __builtin_amdgcn_s_setprio(0);
        // all of this iteration's LDS reads must be complete (not just
        // issued) before any wave can pass the next barrier and overwrite.
        asm volatile("s_waitcnt lgkmcnt(0)" ::: "memory");
        __builtin_amdgcn_sched_barrier(0);
    }

    #pragma unroll
    for (int i = 0; i < 8; i++) {
        const int row0 = m0 + wm * 128 + (i >> 2) * 64 + (i & 3) * 16 + lq * 4;
        #pragma unroll
        for (int nt = 0; nt < 4; nt++) {
            const int col = n0 + wn * 64 + nt * 16 + lr;
            const float bv = bias[col];
            float v[4];
            #pragma unroll
            for (int r = 0; r < 4; r++) v[r] = acc[i][nt][r] + bv;
            if (MODE == 0) {
                #pragma unroll
                for (int r = 0; r < 4; r++)
                    ((float*)Cout)[(size_t)(row0 + r) * N + col] = v[r];
            } else {
                if (n0 < QKW) {
                    #pragma unroll
                    for (int r = 0; r < 4; r++)
                        ((u16*)Cout)[(size_t)(row0 + r) * QKW + col] = f2bf(v[r]);
                } else {
                    const int vcol = col - QKW;          // 0..2047
                    const int b = row0 >> 11, s0 = row0 & 2047;
                    ushort4 pk;
                    pk.x = f2bf(v[0]); pk.y = f2bf(v[1]);
                    pk.z = f2bf(v[2]); pk.w = f2bf(v[3]);
                    *(ushort4*)(vtb + ((size_t)(b*H + (vcol >> 7)) * HD
                                       + (vcol & 127)) * S + s0) = pk;
                }
            }
        }
    }
}

// ---------------------------------------------------------- flash attention
constexpr int TQ = 64, TK = 64;
constexpr int KPAD = 136;
constexpr int VPAD = 72;
constexpr int PPAD = 72;

__global__ __launch_bounds__(256) void attn_kernel(
    const u16* __restrict__ qkb, const u16* __restrict__ vtb,
    u16* __restrict__ ctx)
{
    __shared__ u16 sK[TK * KPAD];
    __shared__ u16 sVT[HD * VPAD];
    __shared__ u16 sP[4 * 16 * PPAD];

    const int flat = blockIdx.x;
    const int qt = 31 - (flat >> 6);
    const int bh = flat & 63;
    const int b  = bh >> 4, h = bh & 15;
    const int q0 = qt * TQ;
    const int t = threadIdx.x;
    const int wave = t >> 6, lane = t & 63;
    const int lr = lane & 15, lq = lane >> 4;

    const u16* baseQK = qkb + (size_t)b * S * QKW + h * HD;
    const u16* baseVT = vtb + (size_t)bh * HD * S;

    const int qrow = q0 + wave * 16 + lr;
    bf16x8 qf[4];
    #pragma unroll
    for (int kc = 0; kc < 4; kc++)
        qf[kc] = *(const bf16x8*)(baseQK + (size_t)qrow * QKW + kc*32 + lq*8);

    float m_r[4], l_r[4];
    f32x4 o[8];
    #pragma unroll
    for (int r = 0; r < 4; r++) { m_r[r] = -1e30f; l_r[r] = 0.0f; }
    #pragma unroll
    for (int j = 0; j < 8; j++) o[j] = (f32x4)(0.0f);

    const float scale = 0.08838834764831845f; // 1/sqrt(128)
    const int nkt = qt + 1;

    for (int kt = 0; kt < nkt; kt++) {
        __syncthreads();
        #pragma unroll
        for (int i = 0; i < 4; i++) {
            int c = t + i * 256;
            int krow = c >> 4, kcol = (c & 15) * 8;
            uint4 v = *(const uint4*)(baseQK + D + (size_t)(kt*TK + krow) * QKW + kcol);
            *(uint4*)(sK + krow * KPAD + kcol) = v;
        }
        #pragma unroll
        for (int i = 0; i < 4; i++) {
            int c = t + i * 256;
            int vrow = c >> 3, coff = (c & 7) * 8;
            uint4 v = *(const uint4*)(baseVT + (size_t)vrow * S + kt*TK + coff);
            *(uint4*)(sVT + vrow * VPAD + coff) = v;
        }
        __syncthreads();

        f32x4 sc[4];
        #pragma unroll
        for (int nt = 0; nt < 4; nt++) sc[nt] = (f32x4)(0.0f);
        #pragma unroll
        for (int nt = 0; nt < 4; nt++)
            #pragma unroll
            for (int kc = 0; kc < 4; kc++) {
                bf16x8 kf = *(const bf16x8*)(sK + (nt*16 + lr) * KPAD + kc*32 + lq*8);
                sc[nt] = __builtin_amdgcn_mfma_f32_16x16x32_bf16(qf[kc], kf, sc[nt], 0, 0, 0);
            }

        const bool diag = (kt == qt);
        float rowmax[4] = {-1e30f, -1e30f, -1e30f, -1e30f};
        const int qgb = q0 + wave*16 + lq*4;
        #pragma unroll
        for (int nt = 0; nt < 4; nt++)
            #pragma unroll
            for (int r = 0; r < 4; r++) {
                float sv = sc[nt][r] * scale;
                if (diag) {
                    const int kg = kt*TK + nt*16 + lr;
                    if (kg > qgb + r) sv = -1e30f;
                }
                sc[nt][r] = sv;
                rowmax[r] = fmaxf(rowmax[r], sv);
            }
        #pragma unroll
        for (int mask = 1; mask < 16; mask <<= 1)
            #pragma unroll
            for (int r = 0; r < 4; r++)
                rowmax[r] = fmaxf(rowmax[r], __shfl_xor(rowmax[r], mask));

        float alpha[4];
        #pragma unroll
        for (int r = 0; r < 4; r++) {
            float nm = fmaxf(m_r[r], rowmax[r]);
            alpha[r] = __expf(m_r[r] - nm);
            m_r[r] = nm;
        }

        u16* pw = sP + wave * 16 * PPAD;
        #pragma unroll
        for (int nt = 0; nt < 4; nt++) {
            #pragma unroll
            for (int r = 0; r < 4; r++) {
                float p = __expf(sc[nt][r] - m_r[r]);
                sc[nt][r] = p;
                pw[(lq*4 + r) * PPAD + nt*16 + lr] = f2bf(p);
            }
        }
        #pragma unroll
        for (int r = 0; r < 4; r++) {
            float psum = sc[0][r] + sc[1][r] + sc[2][r] + sc[3][r];
            l_r[r] = l_r[r] * alpha[r] + psum;
        }
        #pragma unroll
        for (int j = 0; j < 8; j++)
            #pragma unroll
            for (int r = 0; r < 4; r++)
                o[j][r] *= alpha[r];

        #pragma unroll
        for (int kc2 = 0; kc2 < 2; kc2++) {
            bf16x8 pa = *(const bf16x8*)(pw + lr * PPAD + kc2*32 + lq*8);
            #pragma unroll
            for (int n2 = 0; n2 < 8; n2++) {
                bf16x8 vb = *(const bf16x8*)(sVT + (n2*16 + lr) * VPAD + kc2*32 + lq*8);
                o[n2] = __builtin_amdgcn_mfma_f32_16x16x32_bf16(pa, vb, o[n2], 0, 0, 0);
            }
        }
    }

    #pragma unroll
    for (int mask = 1; mask < 16; mask <<= 1)
        #pragma unroll
        for (int r = 0; r < 4; r++)
            l_r[r] += __shfl_xor(l_r[r], mask);
    float inv_l[4];
    #pragma unroll
    for (int r = 0; r < 4; r++) inv_l[r] = 1.0f / l_r[r];
    #pragma unroll
    for (int n2 = 0; n2 < 8; n2++)
        #pragma unroll
        for (int r = 0; r < 4; r++) {
            const int qg = q0 + wave*16 + lq*4 + r;
            const float v = o[n2][r] * inv_l[r];
            ctx[(size_t)(b * S + qg) * D + h * HD + n2*16 + lr] = f2bf(v);
        }
}

// ---------------------------------------------------------------- launcher
extern "C" void kernel_launch(void* const* d_in, const int* in_sizes, int n_in,
                              void* d_out, int out_size, void* d_ws, size_t ws_size,
                              hipStream_t stream) {
    const float* hs    = (const float*)d_in[0];
    const float* gamma = (const float*)d_in[1];
    const float* beta  = (const float*)d_in[2];
    const float* Wqkv  = (const float*)d_in[3];
    const float* bqkv  = (const float*)d_in[4];
    const float* Wproj = (const float*)d_in[5];
    const float* bproj = (const float*)d_in[6];

    char* ws = (char*)d_ws;
    size_t off = 0;
    u16* xb   = (u16*)(ws + off); off += (size_t)ROWS * D * 2;    // 32 MiB
    u16* wtq  = (u16*)(ws + off); off += (size_t)N3D * D * 2;     // 24 MiB
    u16* wtp  = (u16*)(ws + off); off += (size_t)D * D * 2;       //  8 MiB
    u16* qkb  = (u16*)(ws + off); off += (size_t)ROWS * QKW * 2;  // 64 MiB
    u16* vtb  = (u16*)(ws + off); off += (size_t)ROWS * D * 2;    // 32 MiB
    u16* ctxb = (u16*)(ws + off);                                  // 32 MiB

    ln_bf16_kernel<<<ROWS, 256, 0, stream>>>(hs, gamma, beta, xb);
    transpose_bf16_kernel<<<dim3(N3D/64, D/64), 256, 0, stream>>>(Wqkv, wtq, D, N3D);
    transpose_bf16_kernel<<<dim3(D/64,   D/64), 256, 0, stream>>>(Wproj, wtp, D, D);
    gemm256_kernel<2><<<dim3((N3D/BN) * (ROWS/BM)), 512, 0, stream>>>(
        xb, wtq, bqkv, qkb, vtb, ROWS, N3D, D);
    attn_kernel<<<dim3((S/TQ) * BATCH * H), 256, 0, stream>>>(qkb, vtb, ctxb);
    gemm256_kernel<0><<<dim3((D/BN) * (ROWS/BM)), 512, 0, stream>>>(
        ctxb, wtp, bproj, (float*)d_out, nullptr, ROWS, D, D);
}

// Round 6
// 610.341 us; speedup vs baseline: 1.3672x; 1.1162x over previous
//
#include <hip/hip_runtime.h>
#include <cstdint>

typedef __attribute__((ext_vector_type(8))) short bf16x8;
typedef __attribute__((ext_vector_type(4))) float f32x4;
typedef unsigned short u16;
typedef unsigned int u32;

constexpr int D   = 2048;
constexpr int H   = 16;
constexpr int HD  = 128;
constexpr int BATCH = 4;
constexpr int S   = 2048;
constexpr int ROWS = BATCH * S;   // 8192
constexpr int N3D = 3 * D;        // 6144
constexpr int QKW = 2 * D;        // 4096: width of Q|K buffer

__device__ __forceinline__ u16 f2bf(float f) {
    union { float f; u32 u; } v; v.f = f;
    u32 r = v.u + 0x7FFFu + ((v.u >> 16) & 1u);
    return (u16)(r >> 16);
}

__device__ __forceinline__ void gld_lds16(const u16* g, u16* l) {
    __builtin_amdgcn_global_load_lds(
        (const __attribute__((address_space(1))) void*)g,
        (__attribute__((address_space(3))) void*)l, 16, 0, 0);
}

// ---------------------------------------------------------------- LayerNorm
__global__ __launch_bounds__(256) void ln_bf16_kernel(
    const float* __restrict__ x, const float* __restrict__ gamma,
    const float* __restrict__ beta, u16* __restrict__ out)
{
    const int row = blockIdx.x;
    const int t = threadIdx.x;
    const float* xr = x + (size_t)row * D;
    float4 a = ((const float4*)xr)[2*t];
    float4 b = ((const float4*)xr)[2*t+1];
    float s  = a.x+a.y+a.z+a.w + b.x+b.y+b.z+b.w;
    float ss = a.x*a.x+a.y*a.y+a.z*a.z+a.w*a.w + b.x*b.x+b.y*b.y+b.z*b.z+b.w*b.w;
    #pragma unroll
    for (int off = 32; off > 0; off >>= 1) {
        s  += __shfl_down(s, off);
        ss += __shfl_down(ss, off);
    }
    __shared__ float red[8];
    const int wave = t >> 6, lane = t & 63;
    if (lane == 0) { red[wave] = s; red[4+wave] = ss; }
    __syncthreads();
    const float mu   = (red[0]+red[1]+red[2]+red[3]) * (1.0f/D);
    const float var  = (red[4]+red[5]+red[6]+red[7]) * (1.0f/D) - mu*mu;
    const float rstd = rsqrtf(var + 1e-5f);
    float4 g0  = ((const float4*)gamma)[2*t];
    float4 g1  = ((const float4*)gamma)[2*t+1];
    float4 be0 = ((const float4*)beta)[2*t];
    float4 be1 = ((const float4*)beta)[2*t+1];
    union { uint4 v; u16 e[8]; } o;
    o.e[0] = f2bf((a.x-mu)*rstd*g0.x + be0.x);
    o.e[1] = f2bf((a.y-mu)*rstd*g0.y + be0.y);
    o.e[2] = f2bf((a.z-mu)*rstd*g0.z + be0.z);
    o.e[3] = f2bf((a.w-mu)*rstd*g0.w + be0.w);
    o.e[4] = f2bf((b.x-mu)*rstd*g1.x + be1.x);
    o.e[5] = f2bf((b.y-mu)*rstd*g1.y + be1.y);
    o.e[6] = f2bf((b.z-mu)*rstd*g1.z + be1.z);
    o.e[7] = f2bf((b.w-mu)*rstd*g1.w + be1.w);
    ((uint4*)(out + (size_t)row*D))[t] = o.v;
}

// ------------------------------------------- transpose + fp32->bf16 weights
__global__ __launch_bounds__(256) void transpose_bf16_kernel(
    const float* __restrict__ in, u16* __restrict__ out, int K, int N)
{
    __shared__ u16 tile[64][65];
    const int tn0 = blockIdx.x * 64;
    const int tk0 = blockIdx.y * 64;
    const int t = threadIdx.x;
    const int tx = t & 63;
    const int ty = t >> 6;
    #pragma unroll
    for (int i = 0; i < 16; i++) {
        int k = ty + i*4;
        tile[k][tx] = f2bf(in[(size_t)(tk0+k)*N + tn0 + tx]);
    }
    __syncthreads();
    #pragma unroll
    for (int i = 0; i < 16; i++) {
        int n = ty + i*4;
        out[(size_t)(tn0+n)*K + tk0 + tx] = tile[tx][n];
    }
}

// ---------------------------------------------------------------- GEMM 256²
// 256x256 tile, BK=32 sub-tiles in a 4-slot LDS ring (16 KB/slot/operand).
// 8 waves (2M x 4N), per-wave output 128x64.
// PHASE-SPLIT schedule (T3+T4, m201-style barrier pairs, BK-step = 2 phases):
//   phase0: read bfr+af(mh0) | stage A(kt+3) | BAR | lgkm0 | 16 MFMA | BAR
//   phase1: read af(mh1)     | stage B(kt+3) | vmcnt(8) | BAR(publish kt+1)
//           | lgkm0 | 16 MFMA | BAR
// vmcnt(8): 12 loads in flight (tiles kt+1,kt+2 = 8, A+B(kt+3) = 4); wait-to-8
// retires exactly tile kt+1 before its publish barrier. Never vmcnt(0) in loop.
// Overwrite safety: stage of slot (kt-1)&3 is ordered after the closing
// barrier that follows slot (kt-1)'s last readers' lgkmcnt(0).
// XOR bank swizzle (measured-zero conflicts, r3):
//   LDS[row][blk] = global[row][blk ^ ((row>>1)&3)]
// staged via swizzled GLOBAL source, read back rblk = (lq ^ ((lr>>1)&3))*8.
constexpr int BM = 256, BN = 256, BK = 32;

template<int MODE>
__global__ __launch_bounds__(512, 2) void gemm256_kernel(
    const u16* __restrict__ A, const u16* __restrict__ Bt,
    const float* __restrict__ bias, void* __restrict__ Cout,
    u16* __restrict__ vtb, int M, int N, int K)
{
    __shared__ u16 sA[4 * 8192];   // 4 slots x [256][32] bf16 = 64 KB
    __shared__ u16 sB[4 * 8192];   // 64 KB

    const int t = threadIdx.x;
    const int wave = t >> 6, lane = t & 63;
    const int lr = lane & 15, lq = lane >> 4;
    const int wm = wave >> 2, wn = wave & 3;          // 2 x 4 wave grid
    const int m0 = blockIdx.y * BM, n0 = blockIdx.x * BN;

    // staging: granule g (16 B) -> LDS elems [g*8, g*8+8) (linear dest),
    // global source row g>>2, col-block (g&3) ^ ((g>>3)&3)  (XOR swizzle).
    const int g0 = t, g1 = t + 512;
    const int cs0 = ((g0 & 3) ^ ((g0 >> 3) & 3)) * 8;
    const int cs1 = ((g1 & 3) ^ ((g1 >> 3) & 3)) * 8;
    const u16* gA0 = A  + (size_t)(m0 + (g0 >> 2)) * K + cs0;
    const u16* gA1 = A  + (size_t)(m0 + (g1 >> 2)) * K + cs1;
    const u16* gB0 = Bt + (size_t)(n0 + (g0 >> 2)) * K + cs0;
    const u16* gB1 = Bt + (size_t)(n0 + (g1 >> 2)) * K + cs1;

    f32x4 acc[8][4];
    #pragma unroll
    for (int i = 0; i < 8; i++)
        #pragma unroll
        for (int j = 0; j < 4; j++)
            acc[i][j] = (f32x4)(0.0f);

    const int NT = K / BK;   // 64

    auto STAGE_A = [&](int slot, int kt) {
        u16* a = sA + slot * 8192 + wave * 512;
        gld_lds16(gA0 + kt * BK, a);
        gld_lds16(gA1 + kt * BK, a + 4096);
    };
    auto STAGE_B = [&](int slot, int kt) {
        u16* b = sB + slot * 8192 + wave * 512;
        gld_lds16(gB0 + kt * BK, b);
        gld_lds16(gB1 + kt * BK, b + 4096);
    };

    // prologue: tiles 0,1,2 tile-major (12 loads); wait tile 0, publish.
    STAGE_A(0, 0); STAGE_B(0, 0);
    STAGE_A(1, 1); STAGE_B(1, 1);
    STAGE_A(2, 2); STAGE_B(2, 2);
    asm volatile("s_waitcnt vmcnt(8)" ::: "memory");
    __builtin_amdgcn_s_barrier();

    // fragment read: swizzled block for global block lq of row ..+lr
    const int rblk = (lq ^ ((lr >> 1) & 3)) * 8;

    for (int kt = 0; kt < NT; ++kt) {
        const int tp = (kt + 3 < NT) ? (kt + 3) : (NT - 1);
        const int slot3 = (kt + 3) & 3;
        const u16* tAp = sA + (kt & 3) * 8192 + (wm * 128) * BK + rblk;
        const u16* tBp = sB + (kt & 3) * 8192 + (wn * 64)  * BK + rblk;

        // ---------------- phase 0: mhalf 0 ----------------
        bf16x8 bfr[4], af[4];
        #pragma unroll
        for (int nt = 0; nt < 4; nt++)
            bfr[nt] = *(const bf16x8*)(tBp + (nt * 16 + lr) * BK);
        #pragma unroll
        for (int mt = 0; mt < 4; mt++)
            af[mt] = *(const bf16x8*)(tAp + (mt * 16 + lr) * BK);
        STAGE_A(slot3, tp);                    // overwrites slot (kt-1) A: safe
        __builtin_amdgcn_sched_barrier(0);
        __builtin_amdgcn_s_barrier();
        asm volatile("s_waitcnt lgkmcnt(0)" ::: "memory");
        __builtin_amdgcn_sched_barrier(0);
        __builtin_amdgcn_s_setprio(1);
        #pragma unroll
        for (int mt = 0; mt < 4; mt++)
            #pragma unroll
            for (int nt = 0; nt < 4; nt++)
                acc[mt][nt] = __builtin_amdgcn_mfma_f32_16x16x32_bf16(
                    af[mt], bfr[nt], acc[mt][nt], 0, 0, 0);
        __builtin_amdgcn_s_setprio(0);
        __builtin_amdgcn_sched_barrier(0);
        __builtin_amdgcn_s_barrier();

        // ---------------- phase 1: mhalf 1 ----------------
        #pragma unroll
        for (int mt = 0; mt < 4; mt++)
            af[mt] = *(const bf16x8*)(tAp + (64 + mt * 16 + lr) * BK);
        STAGE_B(slot3, tp);                    // overwrites slot (kt-1) B: safe
        // 12 loads in flight; retire tile kt+1 (oldest 4), then publish it.
        asm volatile("s_waitcnt vmcnt(8)" ::: "memory");
        __builtin_amdgcn_sched_barrier(0);
        __builtin_amdgcn_s_barrier();
        asm volatile("s_waitcnt lgkmcnt(0)" ::: "memory");
        __builtin_amdgcn_sched_barrier(0);
        __builtin_amdgcn_s_setprio(1);
        #pragma unroll
        for (int mt = 0; mt < 4; mt++)
            #pragma unroll
            for (int nt = 0; nt < 4; nt++)
                acc[4 + mt][nt] = __builtin_amdgcn_mfma_f32_16x16x32_bf16(
                    af[mt], bfr[nt], acc[4 + mt][nt], 0, 0, 0);
        __builtin_amdgcn_s_setprio(0);
        __builtin_amdgcn_sched_barrier(0);
        __builtin_amdgcn_s_barrier();
    }
    asm volatile("s_waitcnt vmcnt(0)" ::: "memory");

    #pragma unroll
    for (int i = 0; i < 8; i++) {
        const int row0 = m0 + wm * 128 + (i >> 2) * 64 + (i & 3) * 16 + lq * 4;
        #pragma unroll
        for (int nt = 0; nt < 4; nt++) {
            const int col = n0 + wn * 64 + nt * 16 + lr;
            const float bv = bias[col];
            float v[4];
            #pragma unroll
            for (int r = 0; r < 4; r++) v[r] = acc[i][nt][r] + bv;
            if (MODE == 0) {
                #pragma unroll
                for (int r = 0; r < 4; r++)
                    ((float*)Cout)[(size_t)(row0 + r) * N + col] = v[r];
            } else {
                if (n0 < QKW) {
                    #pragma unroll
                    for (int r = 0; r < 4; r++)
                        ((u16*)Cout)[(size_t)(row0 + r) * QKW + col] = f2bf(v[r]);
                } else {
                    const int vcol = col - QKW;          // 0..2047
                    const int b = row0 >> 11, s0 = row0 & 2047;
                    ushort4 pk;
                    pk.x = f2bf(v[0]); pk.y = f2bf(v[1]);
                    pk.z = f2bf(v[2]); pk.w = f2bf(v[3]);
                    *(ushort4*)(vtb + ((size_t)(b*H + (vcol >> 7)) * HD
                                       + (vcol & 127)) * S + s0) = pk;
                }
            }
        }
    }
}

// ---------------------------------------------------------- flash attention
constexpr int TQ = 64, TK = 64;
constexpr int KPAD = 136;
constexpr int VPAD = 72;
constexpr int PPAD = 72;

__global__ __launch_bounds__(256) void attn_kernel(
    const u16* __restrict__ qkb, const u16* __restrict__ vtb,
    u16* __restrict__ ctx)
{
    __shared__ u16 sK[TK * KPAD];
    __shared__ u16 sVT[HD * VPAD];
    __shared__ u16 sP[4 * 16 * PPAD];

    const int flat = blockIdx.x;
    const int qt = 31 - (flat >> 6);
    const int bh = flat & 63;
    const int b  = bh >> 4, h = bh & 15;
    const int q0 = qt * TQ;
    const int t = threadIdx.x;
    const int wave = t >> 6, lane = t & 63;
    const int lr = lane & 15, lq = lane >> 4;

    const u16* baseQK = qkb + (size_t)b * S * QKW + h * HD;
    const u16* baseVT = vtb + (size_t)bh * HD * S;

    const int qrow = q0 + wave * 16 + lr;
    bf16x8 qf[4];
    #pragma unroll
    for (int kc = 0; kc < 4; kc++)
        qf[kc] = *(const bf16x8*)(baseQK + (size_t)qrow * QKW + kc*32 + lq*8);

    float m_r[4], l_r[4];
    f32x4 o[8];
    #pragma unroll
    for (int r = 0; r < 4; r++) { m_r[r] = -1e30f; l_r[r] = 0.0f; }
    #pragma unroll
    for (int j = 0; j < 8; j++) o[j] = (f32x4)(0.0f);

    const float scale = 0.08838834764831845f; // 1/sqrt(128)
    const int nkt = qt + 1;

    for (int kt = 0; kt < nkt; kt++) {
        __syncthreads();
        #pragma unroll
        for (int i = 0; i < 4; i++) {
            int c = t + i * 256;
            int krow = c >> 4, kcol = (c & 15) * 8;
            uint4 v = *(const uint4*)(baseQK + D + (size_t)(kt*TK + krow) * QKW + kcol);
            *(uint4*)(sK + krow * KPAD + kcol) = v;
        }
        #pragma unroll
        for (int i = 0; i < 4; i++) {
            int c = t + i * 256;
            int vrow = c >> 3, coff = (c & 7) * 8;
            uint4 v = *(const uint4*)(baseVT + (size_t)vrow * S + kt*TK + coff);
            *(uint4*)(sVT + vrow * VPAD + coff) = v;
        }
        __syncthreads();

        f32x4 sc[4];
        #pragma unroll
        for (int nt = 0; nt < 4; nt++) sc[nt] = (f32x4)(0.0f);
        #pragma unroll
        for (int nt = 0; nt < 4; nt++)
            #pragma unroll
            for (int kc = 0; kc < 4; kc++) {
                bf16x8 kf = *(const bf16x8*)(sK + (nt*16 + lr) * KPAD + kc*32 + lq*8);
                sc[nt] = __builtin_amdgcn_mfma_f32_16x16x32_bf16(qf[kc], kf, sc[nt], 0, 0, 0);
            }

        const bool diag = (kt == qt);
        float rowmax[4] = {-1e30f, -1e30f, -1e30f, -1e30f};
        const int qgb = q0 + wave*16 + lq*4;
        #pragma unroll
        for (int nt = 0; nt < 4; nt++)
            #pragma unroll
            for (int r = 0; r < 4; r++) {
                float sv = sc[nt][r] * scale;
                if (diag) {
                    const int kg = kt*TK + nt*16 + lr;
                    if (kg > qgb + r) sv = -1e30f;
                }
                sc[nt][r] = sv;
                rowmax[r] = fmaxf(rowmax[r], sv);
            }
        #pragma unroll
        for (int mask = 1; mask < 16; mask <<= 1)
            #pragma unroll
            for (int r = 0; r < 4; r++)
                rowmax[r] = fmaxf(rowmax[r], __shfl_xor(rowmax[r], mask));

        float alpha[4];
        #pragma unroll
        for (int r = 0; r < 4; r++) {
            float nm = fmaxf(m_r[r], rowmax[r]);
            alpha[r] = __expf(m_r[r] - nm);
            m_r[r] = nm;
        }

        u16* pw = sP + wave * 16 * PPAD;
        #pragma unroll
        for (int nt = 0; nt < 4; nt++) {
            #pragma unroll
            for (int r = 0; r < 4; r++) {
                float p = __expf(sc[nt][r] - m_r[r]);
                sc[nt][r] = p;
                pw[(lq*4 + r) * PPAD + nt*16 + lr] = f2bf(p);
            }
        }
        #pragma unroll
        for (int r = 0; r < 4; r++) {
            float psum = sc[0][r] + sc[1][r] + sc[2][r] + sc[3][r];
            l_r[r] = l_r[r] * alpha[r] + psum;
        }
        #pragma unroll
        for (int j = 0; j < 8; j++)
            #pragma unroll
            for (int r = 0; r < 4; r++)
                o[j][r] *= alpha[r];

        #pragma unroll
        for (int kc2 = 0; kc2 < 2; kc2++) {
            bf16x8 pa = *(const bf16x8*)(pw + lr * PPAD + kc2*32 + lq*8);
            #pragma unroll
            for (int n2 = 0; n2 < 8; n2++) {
                bf16x8 vb = *(const bf16x8*)(sVT + (n2*16 + lr) * VPAD + kc2*32 + lq*8);
                o[n2] = __builtin_amdgcn_mfma_f32_16x16x32_bf16(pa, vb, o[n2], 0, 0, 0);
            }
        }
    }

    #pragma unroll
    for (int mask = 1; mask < 16; mask <<= 1)
        #pragma unroll
        for (int r = 0; r < 4; r++)
            l_r[r] += __shfl_xor(l_r[r], mask);
    float inv_l[4];
    #pragma unroll
    for (int r = 0; r < 4; r++) inv_l[r] = 1.0f / l_r[r];
    #pragma unroll
    for (int n2 = 0; n2 < 8; n2++)
        #pragma unroll
        for (int r = 0; r < 4; r++) {
            const int qg = q0 + wave*16 + lq*4 + r;
            const float v = o[n2][r] * inv_l[r];
            ctx[(size_t)(b * S + qg) * D + h * HD + n2*16 + lr] = f2bf(v);
        }
}

// ---------------------------------------------------------------- launcher
extern "C" void kernel_launch(void* const* d_in, const int* in_sizes, int n_in,
                              void* d_out, int out_size, void* d_ws, size_t ws_size,
                              hipStream_t stream) {
    const float* hs    = (const float*)d_in[0];
    const float* gamma = (const float*)d_in[1];
    const float* beta  = (const float*)d_in[2];
    const float* Wqkv  = (const float*)d_in[3];
    const float* bqkv  = (const float*)d_in[4];
    const float* Wproj = (const float*)d_in[5];
    const float* bproj = (const float*)d_in[6];

    char* ws = (char*)d_ws;
    size_t off = 0;
    u16* xb   = (u16*)(ws + off); off += (size_t)ROWS * D * 2;    // 32 MiB
    u16* wtq  = (u16*)(ws + off); off += (size_t)N3D * D * 2;     // 24 MiB
    u16* wtp  = (u16*)(ws + off); off += (size_t)D * D * 2;       //  8 MiB
    u16* qkb  = (u16*)(ws + off); off += (size_t)ROWS * QKW * 2;  // 64 MiB
    u16* vtb  = (u16*)(ws + off); off += (size_t)ROWS * D * 2;    // 32 MiB
    u16* ctxb = (u16*)(ws + off);                                  // 32 MiB

    ln_bf16_kernel<<<ROWS, 256, 0, stream>>>(hs, gamma, beta, xb);
    transpose_bf16_kernel<<<dim3(N3D/64, D/64), 256, 0, stream>>>(Wqkv, wtq, D, N3D);
    transpose_bf16_kernel<<<dim3(D/64,   D/64), 256, 0, stream>>>(Wproj, wtp, D, D);
    gemm256_kernel<2><<<dim3(N3D/BN, ROWS/BM), 512, 0, stream>>>(
        xb, wtq, bqkv, qkb, vtb, ROWS, N3D, D);
    attn_kernel<<<dim3((S/TQ) * BATCH * H), 256, 0, stream>>>(qkb, vtb, ctxb);
    gemm256_kernel<0><<<dim3(D/BN, ROWS/BM), 512, 0, stream>>>(
        ctxb, wtp, bproj, (float*)d_out, nullptr, ROWS, D, D);
}

// Round 7
// 577.845 us; speedup vs baseline: 1.4441x; 1.0562x over previous
//
#include <hip/hip_runtime.h>
#include <cstdint>

typedef __attribute__((ext_vector_type(8))) short bf16x8;
typedef __attribute__((ext_vector_type(4))) float f32x4;
typedef unsigned short u16;
typedef unsigned int u32;

constexpr int D   = 2048;
constexpr int H   = 16;
constexpr int HD  = 128;
constexpr int BATCH = 4;
constexpr int S   = 2048;
constexpr int ROWS = BATCH * S;   // 8192
constexpr int N3D = 3 * D;        // 6144
constexpr int QKW = 2 * D;        // 4096: width of Q|K buffer

__device__ __forceinline__ u16 f2bf(float f) {
    union { float f; u32 u; } v; v.f = f;
    u32 r = v.u + 0x7FFFu + ((v.u >> 16) & 1u);
    return (u16)(r >> 16);
}

__device__ __forceinline__ void gld_lds16(const u16* g, u16* l) {
    __builtin_amdgcn_global_load_lds(
        (const __attribute__((address_space(1))) void*)g,
        (__attribute__((address_space(3))) void*)l, 16, 0, 0);
}

// ---------------------------------------------------------------- LayerNorm
__global__ __launch_bounds__(256) void ln_bf16_kernel(
    const float* __restrict__ x, const float* __restrict__ gamma,
    const float* __restrict__ beta, u16* __restrict__ out)
{
    const int row = blockIdx.x;
    const int t = threadIdx.x;
    const float* xr = x + (size_t)row * D;
    float4 a = ((const float4*)xr)[2*t];
    float4 b = ((const float4*)xr)[2*t+1];
    float s  = a.x+a.y+a.z+a.w + b.x+b.y+b.z+b.w;
    float ss = a.x*a.x+a.y*a.y+a.z*a.z+a.w*a.w + b.x*b.x+b.y*b.y+b.z*b.z+b.w*b.w;
    #pragma unroll
    for (int off = 32; off > 0; off >>= 1) {
        s  += __shfl_down(s, off);
        ss += __shfl_down(ss, off);
    }
    __shared__ float red[8];
    const int wave = t >> 6, lane = t & 63;
    if (lane == 0) { red[wave] = s; red[4+wave] = ss; }
    __syncthreads();
    const float mu   = (red[0]+red[1]+red[2]+red[3]) * (1.0f/D);
    const float var  = (red[4]+red[5]+red[6]+red[7]) * (1.0f/D) - mu*mu;
    const float rstd = rsqrtf(var + 1e-5f);
    float4 g0  = ((const float4*)gamma)[2*t];
    float4 g1  = ((const float4*)gamma)[2*t+1];
    float4 be0 = ((const float4*)beta)[2*t];
    float4 be1 = ((const float4*)beta)[2*t+1];
    union { uint4 v; u16 e[8]; } o;
    o.e[0] = f2bf((a.x-mu)*rstd*g0.x + be0.x);
    o.e[1] = f2bf((a.y-mu)*rstd*g0.y + be0.y);
    o.e[2] = f2bf((a.z-mu)*rstd*g0.z + be0.z);
    o.e[3] = f2bf((a.w-mu)*rstd*g0.w + be0.w);
    o.e[4] = f2bf((b.x-mu)*rstd*g1.x + be1.x);
    o.e[5] = f2bf((b.y-mu)*rstd*g1.y + be1.y);
    o.e[6] = f2bf((b.z-mu)*rstd*g1.z + be1.z);
    o.e[7] = f2bf((b.w-mu)*rstd*g1.w + be1.w);
    ((uint4*)(out + (size_t)row*D))[t] = o.v;
}

// ------------------------------------------- transpose + fp32->bf16 weights
__global__ __launch_bounds__(256) void transpose_bf16_kernel(
    const float* __restrict__ in, u16* __restrict__ out, int K, int N)
{
    __shared__ u16 tile[64][65];
    const int tn0 = blockIdx.x * 64;
    const int tk0 = blockIdx.y * 64;
    const int t = threadIdx.x;
    const int tx = t & 63;
    const int ty = t >> 6;
    #pragma unroll
    for (int i = 0; i < 16; i++) {
        int k = ty + i*4;
        tile[k][tx] = f2bf(in[(size_t)(tk0+k)*N + tn0 + tx]);
    }
    __syncthreads();
    #pragma unroll
    for (int i = 0; i < 16; i++) {
        int n = ty + i*4;
        out[(size_t)(tn0+n)*K + tk0 + tx] = tile[tx][n];
    }
}

// ---------------------------------------------------------------- GEMM 256²
// (r6 structure, unchanged — verified 219 µs / MfmaUtil 41%)
constexpr int BM = 256, BN = 256, BK = 32;

template<int MODE>
__global__ __launch_bounds__(512, 2) void gemm256_kernel(
    const u16* __restrict__ A, const u16* __restrict__ Bt,
    const float* __restrict__ bias, void* __restrict__ Cout,
    u16* __restrict__ vtb, int M, int N, int K)
{
    __shared__ u16 sA[4 * 8192];   // 4 slots x [256][32] bf16 = 64 KB
    __shared__ u16 sB[4 * 8192];   // 64 KB

    const int t = threadIdx.x;
    const int wave = t >> 6, lane = t & 63;
    const int lr = lane & 15, lq = lane >> 4;
    const int wm = wave >> 2, wn = wave & 3;          // 2 x 4 wave grid
    const int m0 = blockIdx.y * BM, n0 = blockIdx.x * BN;

    const int g0 = t, g1 = t + 512;
    const int cs0 = ((g0 & 3) ^ ((g0 >> 3) & 3)) * 8;
    const int cs1 = ((g1 & 3) ^ ((g1 >> 3) & 3)) * 8;
    const u16* gA0 = A  + (size_t)(m0 + (g0 >> 2)) * K + cs0;
    const u16* gA1 = A  + (size_t)(m0 + (g1 >> 2)) * K + cs1;
    const u16* gB0 = Bt + (size_t)(n0 + (g0 >> 2)) * K + cs0;
    const u16* gB1 = Bt + (size_t)(n0 + (g1 >> 2)) * K + cs1;

    f32x4 acc[8][4];
    #pragma unroll
    for (int i = 0; i < 8; i++)
        #pragma unroll
        for (int j = 0; j < 4; j++)
            acc[i][j] = (f32x4)(0.0f);

    const int NT = K / BK;   // 64

    auto STAGE_A = [&](int slot, int kt) {
        u16* a = sA + slot * 8192 + wave * 512;
        gld_lds16(gA0 + kt * BK, a);
        gld_lds16(gA1 + kt * BK, a + 4096);
    };
    auto STAGE_B = [&](int slot, int kt) {
        u16* b = sB + slot * 8192 + wave * 512;
        gld_lds16(gB0 + kt * BK, b);
        gld_lds16(gB1 + kt * BK, b + 4096);
    };

    STAGE_A(0, 0); STAGE_B(0, 0);
    STAGE_A(1, 1); STAGE_B(1, 1);
    STAGE_A(2, 2); STAGE_B(2, 2);
    asm volatile("s_waitcnt vmcnt(8)" ::: "memory");
    __builtin_amdgcn_s_barrier();

    const int rblk = (lq ^ ((lr >> 1) & 3)) * 8;

    for (int kt = 0; kt < NT; ++kt) {
        const int tp = (kt + 3 < NT) ? (kt + 3) : (NT - 1);
        const int slot3 = (kt + 3) & 3;
        const u16* tAp = sA + (kt & 3) * 8192 + (wm * 128) * BK + rblk;
        const u16* tBp = sB + (kt & 3) * 8192 + (wn * 64)  * BK + rblk;

        // ---------------- phase 0: mhalf 0 ----------------
        bf16x8 bfr[4], af[4];
        #pragma unroll
        for (int nt = 0; nt < 4; nt++)
            bfr[nt] = *(const bf16x8*)(tBp + (nt * 16 + lr) * BK);
        #pragma unroll
        for (int mt = 0; mt < 4; mt++)
            af[mt] = *(const bf16x8*)(tAp + (mt * 16 + lr) * BK);
        STAGE_A(slot3, tp);
        __builtin_amdgcn_sched_barrier(0);
        __builtin_amdgcn_s_barrier();
        asm volatile("s_waitcnt lgkmcnt(0)" ::: "memory");
        __builtin_amdgcn_sched_barrier(0);
        __builtin_amdgcn_s_setprio(1);
        #pragma unroll
        for (int mt = 0; mt < 4; mt++)
            #pragma unroll
            for (int nt = 0; nt < 4; nt++)
                acc[mt][nt] = __builtin_amdgcn_mfma_f32_16x16x32_bf16(
                    af[mt], bfr[nt], acc[mt][nt], 0, 0, 0);
        __builtin_amdgcn_s_setprio(0);
        __builtin_amdgcn_sched_barrier(0);
        __builtin_amdgcn_s_barrier();

        // ---------------- phase 1: mhalf 1 ----------------
        #pragma unroll
        for (int mt = 0; mt < 4; mt++)
            af[mt] = *(const bf16x8*)(tAp + (64 + mt * 16 + lr) * BK);
        STAGE_B(slot3, tp);
        asm volatile("s_waitcnt vmcnt(8)" ::: "memory");
        __builtin_amdgcn_sched_barrier(0);
        __builtin_amdgcn_s_barrier();
        asm volatile("s_waitcnt lgkmcnt(0)" ::: "memory");
        __builtin_amdgcn_sched_barrier(0);
        __builtin_amdgcn_s_setprio(1);
        #pragma unroll
        for (int mt = 0; mt < 4; mt++)
            #pragma unroll
            for (int nt = 0; nt < 4; nt++)
                acc[4 + mt][nt] = __builtin_amdgcn_mfma_f32_16x16x32_bf16(
                    af[mt], bfr[nt], acc[4 + mt][nt], 0, 0, 0);
        __builtin_amdgcn_s_setprio(0);
        __builtin_amdgcn_sched_barrier(0);
        __builtin_amdgcn_s_barrier();
    }
    asm volatile("s_waitcnt vmcnt(0)" ::: "memory");

    #pragma unroll
    for (int i = 0; i < 8; i++) {
        const int row0 = m0 + wm * 128 + (i >> 2) * 64 + (i & 3) * 16 + lq * 4;
        #pragma unroll
        for (int nt = 0; nt < 4; nt++) {
            const int col = n0 + wn * 64 + nt * 16 + lr;
            const float bv = bias[col];
            float v[4];
            #pragma unroll
            for (int r = 0; r < 4; r++) v[r] = acc[i][nt][r] + bv;
            if (MODE == 0) {
                #pragma unroll
                for (int r = 0; r < 4; r++)
                    ((float*)Cout)[(size_t)(row0 + r) * N + col] = v[r];
            } else {
                if (n0 < QKW) {
                    #pragma unroll
                    for (int r = 0; r < 4; r++)
                        ((u16*)Cout)[(size_t)(row0 + r) * QKW + col] = f2bf(v[r]);
                } else {
                    const int vcol = col - QKW;          // 0..2047
                    const int b = row0 >> 11, s0 = row0 & 2047;
                    ushort4 pk;
                    pk.x = f2bf(v[0]); pk.y = f2bf(v[1]);
                    pk.z = f2bf(v[2]); pk.w = f2bf(v[3]);
                    *(ushort4*)(vtb + ((size_t)(b*H + (vcol >> 7)) * HD
                                       + (vcol & 127)) * S + s0) = pk;
                }
            }
        }
    }
}

// ---------------------------------------------------------- flash attention
// Double-buffered direct-to-LDS K/V staging (global_load_lds), XOR column
// swizzle (K: cb^(row&15), V^T: cb^(row&7)) applied on the per-lane GLOBAL
// source, undone on the LDS read (same involution both sides, rule #21).
// Per tile: one __syncthreads (its vmcnt-drain waits on loads issued one
// full tile ago = ~free, and guards buffer reuse), then issue tile kt+1's
// 8 global_load_lds per wave, then compute tile kt. T5 setprio on MFMAs.
constexpr int TQ = 64, TK = 64;
constexpr int PPAD = 72;

__global__ __launch_bounds__(256) void attn_kernel(
    const u16* __restrict__ qkb, const u16* __restrict__ vtb,
    u16* __restrict__ ctx)
{
    __shared__ u16 sK[2 * TK * HD];    // [2][64][128] swizzled  32 KB
    __shared__ u16 sVT[2 * HD * TK];   // [2][128][64] swizzled  32 KB
    __shared__ u16 sP[4 * 16 * PPAD];  //                          9 KB

    const int flat = blockIdx.x;
    const int qt = 31 - (flat >> 6);
    const int bh = flat & 63;
    const int b  = bh >> 4, h = bh & 15;
    const int q0 = qt * TQ;
    const int t = threadIdx.x;
    const int wave = t >> 6, lane = t & 63;
    const int lr = lane & 15, lq = lane >> 4;

    const u16* baseQK = qkb + (size_t)b * S * QKW + h * HD;
    const u16* baseVT = vtb + (size_t)bh * HD * S;

    const int qrow = q0 + wave * 16 + lr;
    bf16x8 qf[4];
    #pragma unroll
    for (int kc = 0; kc < 4; kc++)
        qf[kc] = *(const bf16x8*)(baseQK + (size_t)qrow * QKW + kc*32 + lq*8);

    // per-lane staging sources (tile 0); K granule g = wave*256+i*64+lane:
    //   row = g>>4 = wave*16+i*4+(lane>>4), cb = lane&15,
    //   src col-block = cb ^ (row&15) = (lane&15) ^ (i*4 + (lane>>4))
    // V granule: row = g>>3 = wave*32+i*8+(lane>>3), cb = lane&7,
    //   src col-block = (lane&7) ^ (lane>>3)
    const u16* kptr0; const u16* kptr1; const u16* kptr2; const u16* kptr3;
    {
        const int r0 = wave*16 + (lane>>4);
        kptr0 = baseQK + D + (size_t)(r0     ) * QKW + (((lane&15) ^ ( 0 + (lane>>4))) * 8);
        kptr1 = baseQK + D + (size_t)(r0 +  4) * QKW + (((lane&15) ^ ( 4 + (lane>>4))) * 8);
        kptr2 = baseQK + D + (size_t)(r0 +  8) * QKW + (((lane&15) ^ ( 8 + (lane>>4))) * 8);
        kptr3 = baseQK + D + (size_t)(r0 + 12) * QKW + (((lane&15) ^ (12 + (lane>>4))) * 8);
    }
    const int vcbs = ((lane & 7) ^ (lane >> 3)) * 8;
    const int vr0 = wave*32 + (lane>>3);
    const u16* vptr0 = baseVT + (size_t)(vr0     ) * S + vcbs;
    const u16* vptr1 = baseVT + (size_t)(vr0 +  8) * S + vcbs;
    const u16* vptr2 = baseVT + (size_t)(vr0 + 16) * S + vcbs;
    const u16* vptr3 = baseVT + (size_t)(vr0 + 24) * S + vcbs;

    auto STAGE = [&](int buf, int kt) {
        u16* kd = sK  + buf * 8192 + wave * 2048;
        u16* vd = sVT + buf * 8192 + wave * 2048;
        const size_t ko = (size_t)(kt * TK) * QKW;
        const int vo = kt * TK;
        gld_lds16(kptr0 + ko, kd);
        gld_lds16(kptr1 + ko, kd + 512);
        gld_lds16(kptr2 + ko, kd + 1024);
        gld_lds16(kptr3 + ko, kd + 1536);
        gld_lds16(vptr0 + vo, vd);
        gld_lds16(vptr1 + vo, vd + 512);
        gld_lds16(vptr2 + vo, vd + 1024);
        gld_lds16(vptr3 + vo, vd + 1536);
    };

    float m_r[4], l_r[4];
    f32x4 o[8];
    #pragma unroll
    for (int r = 0; r < 4; r++) { m_r[r] = -1e30f; l_r[r] = 0.0f; }
    #pragma unroll
    for (int j = 0; j < 8; j++) o[j] = (f32x4)(0.0f);

    const float scale = 0.08838834764831845f; // 1/sqrt(128)
    const int nkt = qt + 1;

    STAGE(0, 0);

    for (int kt = 0; kt < nkt; kt++) {
        // drains this wave's stage loads (issued a full tile ago) and
        // guards reuse of buffer (kt+1)&1 (its readers finished iter kt-1).
        __syncthreads();
        if (kt + 1 < nkt) STAGE((kt + 1) & 1, kt + 1);

        const u16* Kb = sK  + (kt & 1) * 8192;
        const u16* Vb = sVT + (kt & 1) * 8192;

        f32x4 sc[4];
        #pragma unroll
        for (int nt = 0; nt < 4; nt++) sc[nt] = (f32x4)(0.0f);
        __builtin_amdgcn_s_setprio(1);
        #pragma unroll
        for (int nt = 0; nt < 4; nt++)
            #pragma unroll
            for (int kc = 0; kc < 4; kc++) {
                bf16x8 kf = *(const bf16x8*)(Kb + (nt*16 + lr) * HD
                                             + (((kc*4 + lq) ^ lr) * 8));
                sc[nt] = __builtin_amdgcn_mfma_f32_16x16x32_bf16(qf[kc], kf, sc[nt], 0, 0, 0);
            }
        __builtin_amdgcn_s_setprio(0);

        const bool diag = (kt == qt);
        float rowmax[4] = {-1e30f, -1e30f, -1e30f, -1e30f};
        const int qgb = q0 + wave*16 + lq*4;
        #pragma unroll
        for (int nt = 0; nt < 4; nt++)
            #pragma unroll
            for (int r = 0; r < 4; r++) {
                float sv = sc[nt][r] * scale;
                if (diag) {
                    const int kg = kt*TK + nt*16 + lr;
                    if (kg > qgb + r) sv = -1e30f;
                }
                sc[nt][r] = sv;
                rowmax[r] = fmaxf(rowmax[r], sv);
            }
        #pragma unroll
        for (int mask = 1; mask < 16; mask <<= 1)
            #pragma unroll
            for (int r = 0; r < 4; r++)
                rowmax[r] = fmaxf(rowmax[r], __shfl_xor(rowmax[r], mask));

        float alpha[4];
        #pragma unroll
        for (int r = 0; r < 4; r++) {
            float nm = fmaxf(m_r[r], rowmax[r]);
            alpha[r] = __expf(m_r[r] - nm);
            m_r[r] = nm;
        }

        u16* pw = sP + wave * 16 * PPAD;
        #pragma unroll
        for (int nt = 0; nt < 4; nt++) {
            #pragma unroll
            for (int r = 0; r < 4; r++) {
                float p = __expf(sc[nt][r] - m_r[r]);
                sc[nt][r] = p;
                pw[(lq*4 + r) * PPAD + nt*16 + lr] = f2bf(p);
            }
        }
        #pragma unroll
        for (int r = 0; r < 4; r++) {
            float psum = sc[0][r] + sc[1][r] + sc[2][r] + sc[3][r];
            l_r[r] = l_r[r] * alpha[r] + psum;
        }
        #pragma unroll
        for (int j = 0; j < 8; j++)
            #pragma unroll
            for (int r = 0; r < 4; r++)
                o[j][r] *= alpha[r];

        #pragma unroll
        for (int kc2 = 0; kc2 < 2; kc2++) {
            bf16x8 pa = *(const bf16x8*)(pw + lr * PPAD + kc2*32 + lq*8);
            __builtin_amdgcn_s_setprio(1);
            #pragma unroll
            for (int n2 = 0; n2 < 8; n2++) {
                bf16x8 vb = *(const bf16x8*)(Vb + (n2*16 + lr) * TK
                                             + ((((kc2*4) + lq) ^ (lr & 7)) * 8));
                o[n2] = __builtin_amdgcn_mfma_f32_16x16x32_bf16(pa, vb, o[n2], 0, 0, 0);
            }
            __builtin_amdgcn_s_setprio(0);
        }
    }

    #pragma unroll
    for (int mask = 1; mask < 16; mask <<= 1)
        #pragma unroll
        for (int r = 0; r < 4; r++)
            l_r[r] += __shfl_xor(l_r[r], mask);
    float inv_l[4];
    #pragma unroll
    for (int r = 0; r < 4; r++) inv_l[r] = 1.0f / l_r[r];
    #pragma unroll
    for (int n2 = 0; n2 < 8; n2++)
        #pragma unroll
        for (int r = 0; r < 4; r++) {
            const int qg = q0 + wave*16 + lq*4 + r;
            const float v = o[n2][r] * inv_l[r];
            ctx[(size_t)(b * S + qg) * D + h * HD + n2*16 + lr] = f2bf(v);
        }
}

// ---------------------------------------------------------------- launcher
extern "C" void kernel_launch(void* const* d_in, const int* in_sizes, int n_in,
                              void* d_out, int out_size, void* d_ws, size_t ws_size,
                              hipStream_t stream) {
    const float* hs    = (const float*)d_in[0];
    const float* gamma = (const float*)d_in[1];
    const float* beta  = (const float*)d_in[2];
    const float* Wqkv  = (const float*)d_in[3];
    const float* bqkv  = (const float*)d_in[4];
    const float* Wproj = (const float*)d_in[5];
    const float* bproj = (const float*)d_in[6];

    char* ws = (char*)d_ws;
    size_t off = 0;
    u16* xb   = (u16*)(ws + off); off += (size_t)ROWS * D * 2;    // 32 MiB
    u16* wtq  = (u16*)(ws + off); off += (size_t)N3D * D * 2;     // 24 MiB
    u16* wtp  = (u16*)(ws + off); off += (size_t)D * D * 2;       //  8 MiB
    u16* qkb  = (u16*)(ws + off); off += (size_t)ROWS * QKW * 2;  // 64 MiB
    u16* vtb  = (u16*)(ws + off); off += (size_t)ROWS * D * 2;    // 32 MiB
    u16* ctxb = (u16*)(ws + off);                                  // 32 MiB

    ln_bf16_kernel<<<ROWS, 256, 0, stream>>>(hs, gamma, beta, xb);
    transpose_bf16_kernel<<<dim3(N3D/64, D/64), 256, 0, stream>>>(Wqkv, wtq, D, N3D);
    transpose_bf16_kernel<<<dim3(D/64,   D/64), 256, 0, stream>>>(Wproj, wtp, D, D);
    gemm256_kernel<2><<<dim3(N3D/BN, ROWS/BM), 512, 0, stream>>>(
        xb, wtq, bqkv, qkb, vtb, ROWS, N3D, D);
    attn_kernel<<<dim3((S/TQ) * BATCH * H), 256, 0, stream>>>(qkb, vtb, ctxb);
    gemm256_kernel<0><<<dim3(D/BN, ROWS/BM), 512, 0, stream>>>(
        ctxb, wtp, bproj, (float*)d_out, nullptr, ROWS, D, D);
}